// Round 1
// baseline (472.359 us; speedup 1.0000x reference)
//
#include <hip/hip_runtime.h>

// Problem constants
#define B_   2
#define NQ_  8192
#define NK_  8192
#define DIN_ 256
#define DH_  256
#define M_   (B_ * NQ_)   // 16384 flattened rows

typedef _Float16 f16x8 __attribute__((ext_vector_type(8)));
typedef unsigned short u16x8 __attribute__((ext_vector_type(8)));
typedef unsigned short u16x4 __attribute__((ext_vector_type(4)));
typedef unsigned int  u32x4 __attribute__((ext_vector_type(4)));
typedef float f32x16 __attribute__((ext_vector_type(16)));

// fp32 -> fp16 bits (RTNE via hardware cvt)
__device__ __forceinline__ unsigned short f2h(float f) {
    _Float16 h = (_Float16)f;
    return __builtin_bit_cast(unsigned short, h);
}
__device__ __forceinline__ float h2f(unsigned short u) {
    return (float)__builtin_bit_cast(_Float16, u);
}

// ---------------------------------------------------------------------------
// Kernel 1: weight convert + transpose via LDS tile (both sides coalesced).
// wt[mat][n][k] = fp16(W[mat][k][n]).  grid (4,4,3), block 256.  (unchanged)
// ---------------------------------------------------------------------------
__global__ void wt_conv(const float* __restrict__ Wq, const float* __restrict__ Wk,
                        const float* __restrict__ Wv, unsigned short* __restrict__ wt) {
    __shared__ float tile[64][65];
    const int mat = blockIdx.z;
    const int k0 = blockIdx.x * 64, n0 = blockIdx.y * 64;
    const float* W = (mat == 0) ? Wq : (mat == 1) ? Wk : Wv;
#pragma unroll
    for (int p = 0; p < 16; ++p) {
        const int idx = p * 256 + threadIdx.x;
        const int r = idx >> 6, c = idx & 63;
        tile[r][c] = W[(k0 + r) * 256 + n0 + c];
    }
    __syncthreads();
#pragma unroll
    for (int p = 0; p < 16; ++p) {
        const int idx = p * 256 + threadIdx.x;
        const int nr = idx >> 6, kc = idx & 63;
        wt[mat * 65536 + (n0 + nr) * 256 + k0 + kc] = f2h(tile[kc][nr]);
    }
}

// ---------------------------------------------------------------------------
// Kernel 2: projections (unchanged).
// ---------------------------------------------------------------------------
__global__ __launch_bounds__(256) void proj(
    const float* __restrict__ xq, const float* __restrict__ xk, const float* __restrict__ xv,
    const float* __restrict__ bq, const float* __restrict__ bk, const float* __restrict__ bv,
    const unsigned short* __restrict__ wt,
    unsigned short* __restrict__ q_emb, unsigned short* __restrict__ k_emb,
    unsigned short* __restrict__ v_emb_t) {
    const int mat = blockIdx.y;
    const float* x    = (mat == 0) ? xq : (mat == 1) ? xk : xv;
    const float* bias = (mat == 0) ? bq : (mat == 1) ? bk : bv;
    const unsigned short* w = wt + mat * 65536;

    const int tid = threadIdx.x;
    const int l = tid & 63, wv = tid >> 6;
    const int pair = wv >> 1, h = wv & 1;
    const int lm = l & 31, lh = l >> 5;
    const int row0 = blockIdx.x * 64;
    const int m = row0 + pair * 32 + lm;

    f32x16 acc[4];
#pragma unroll
    for (int i = 0; i < 4; ++i)
#pragma unroll
        for (int j = 0; j < 16; ++j) acc[i][j] = 0.0f;

#pragma unroll
    for (int ks = 0; ks < 16; ++ks) {
        const float4* ap = (const float4*)(x + (size_t)m * 256 + ks * 16 + lh * 8);
        float4 a0 = ap[0], a1 = ap[1];
        u16x8 au;
        au[0] = f2h(a0.x); au[1] = f2h(a0.y); au[2] = f2h(a0.z); au[3] = f2h(a0.w);
        au[4] = f2h(a1.x); au[5] = f2h(a1.y); au[6] = f2h(a1.z); au[7] = f2h(a1.w);
        f16x8 af = __builtin_bit_cast(f16x8, au);
#pragma unroll
        for (int nt = 0; nt < 4; ++nt) {
            f16x8 bfr = *(const f16x8*)(w + (h * 128 + nt * 32 + lm) * 256 + ks * 16 + lh * 8);
            acc[nt] = __builtin_amdgcn_mfma_f32_32x32x16_f16(af, bfr, acc[nt], 0, 0, 0);
        }
    }

    if (mat < 2) {
        unsigned short* emb = (mat == 0) ? q_emb : k_emb;
#pragma unroll
        for (int nt = 0; nt < 4; ++nt) {
            const int n = h * 128 + nt * 32 + lm;
            const float bsv = bias[n];
#pragma unroll
            for (int r = 0; r < 16; ++r) {
                const int rl = (r & 3) + 8 * (r >> 2) + 4 * lh;
                emb[(size_t)(row0 + pair * 32 + rl) * 256 + n] = f2h(acc[nt][r] + bsv);
            }
        }
    } else {
        const int batch = row0 >> 13;
        const int nqb = (row0 & 8191) + pair * 32;
#pragma unroll
        for (int nt = 0; nt < 4; ++nt) {
            const int n = h * 128 + nt * 32 + lm;   // output feature d
            const float bsv = bias[n];
            unsigned short* dst = v_emb_t + (size_t)batch * DH_ * NQ_ + (size_t)n * NQ_ + nqb;
#pragma unroll
            for (int g = 0; g < 4; ++g) {
                u16x4 pk;
#pragma unroll
                for (int j = 0; j < 4; ++j) pk[j] = f2h(acc[nt][4 * g + j] + bsv);
                *(u16x4*)(dst + 8 * g + 4 * lh) = pk;   // rows nqb+8g+4lh .. +3
            }
        }
    }
}

// ---------------------------------------------------------------------------
// Kernel 3: flash attention v2.
//   - K staged by global_load_lds (dwordx4) into a DOUBLE buffer, XOR granule
//     swizzle applied on the *global source* address (LDS dest stays linear);
//     read side applies the same swizzle -> conflict-free without padding.
//   - V fragments live entirely in registers, loaded direct from global (L2-
//     resident) one iteration ahead.  No V LDS, no staging VALU.
//   - 2 barriers/iter: B3 = lgkmcnt(0)+raw s_barrier (no vmcnt drain, K-DMA
//     and V prefetch stay in flight); B4 = __syncthreads (its vmcnt(0) drain
//     is exactly the wait the K-DMA for the next tile needs).
//   - Defer-max (THR=8): skip O-rescale when max growth is small; decision is
//     uniform across the 4 kq waves sharing each q row.
// ---------------------------------------------------------------------------
#define BN_ 128
#define NT_ (NK_ / BN_)                    // 64 iterations
#define KB_BYTES 65536                     // 128 rows x 512B, swizzled granules
#define PSTRIDE 272                        // 64 rows x (256 + 16) : proven pad
#define PBYTES  (64 * PSTRIDE)             // 17408
#define STAT_OFF (2 * KB_BYTES + PBYTES)   // 148480
#define LDS_TOTAL (STAT_OFF + 2048)        // 150528 <= 160 KiB

__global__ __launch_bounds__(512, 2) void flash(
    const unsigned short* __restrict__ q_emb, const unsigned short* __restrict__ k_emb,
    const unsigned short* __restrict__ v_emb_t, float* __restrict__ out) {
    __shared__ __align__(16) char lds_raw[LDS_TOTAL];
    char* pbuf = lds_raw + 2 * KB_BYTES;        // [64][272]
    float* smax = (float*)(lds_raw + STAT_OFF); // [2][32][4]
    float* ssum = smax + 256;                   // [2][32][4]

    const int tid = threadIdx.x;
    const int l = tid & 63, wv = tid >> 6;      // wv 0..7
    const int kq = wv >> 1, pair = wv & 1;      // k-tile / q-tile role
    const int lm = l & 31, lh = l >> 5;

    const int bx = blockIdx.x;
    const int batch = bx >> 7;
    const int qb = (bx & 127) * 64;

    const unsigned short* kg = k_emb + (size_t)batch * NK_ * 256;
    const unsigned short* vg = v_emb_t + (size_t)batch * DH_ * NQ_;

    // Q fragments register-resident: q row = qb + pair*32 + lm, all 256 dims.
    const int mrow = batch * NQ_ + qb + pair * 32 + lm;
    f16x8 qf[16];
#pragma unroll
    for (int ks = 0; ks < 16; ++ks)
        qf[ks] = *(const f16x8*)(q_emb + (size_t)mrow * 256 + ks * 16 + lh * 8);

    // O^T accumulator: this wave's d-quarter (kq), q cols = pair tile.
    f32x16 oacc[2];
#pragma unroll
    for (int i = 0; i < 2; ++i)
#pragma unroll
        for (int j = 0; j < 16; ++j) oacc[i][j] = 0.0f;

    float mstat = -3.0e38f, lstat = 0.0f;

    // ---- K staging via global_load_lds: wave wv owns rows wv*16..wv*16+15.
    // LDS layout: row*512 + gsw*16, gsw = g ^ (row&31)  (granule = 16B).
    // DMA writes linearly (base + lane*16); swizzle folded into the SOURCE.
    const int rlane = l >> 5;                  // +0/+1 row within 1KB chunk
    const int gl = l & 31;                     // linear granule this lane fills
    auto stage_k = [&](int kb, char* kdst) {
#pragma unroll
        for (int p = 0; p < 8; ++p) {
            const int r0 = wv * 16 + 2 * p;            // wave-uniform base row
            const int r = r0 + rlane;
            const int gsw = gl ^ (r & 31);             // source granule
            const unsigned short* src = kg + (size_t)(kb + r) * 256 + gsw * 8;
            __builtin_amdgcn_global_load_lds(
                (const __attribute__((address_space(1))) void*)src,
                (__attribute__((address_space(3))) void*)(kdst + r0 * 512),
                16, 0, 0);
        }
    };

    // ---- V fragments direct-from-global into registers (prefetched 1 iter
    // ahead).  vf[ks2*2+dt] : rows d = kq*64+dt*32+lm, k cols ks2*16+lh*8.
    f16x8 vf[16];
    const unsigned short* vgw = vg + (size_t)(kq * 64 + lm) * NQ_ + lh * 8;
    auto load_v = [&](int kb) {
#pragma unroll
        for (int ks2 = 0; ks2 < 8; ++ks2)
#pragma unroll
            for (int dt = 0; dt < 2; ++dt)
                vf[ks2 * 2 + dt] =
                    *(const f16x8*)(vgw + (size_t)dt * 32 * NQ_ + kb + ks2 * 16);
    };

    // prologue: tile 0
    stage_k(0, lds_raw);
    load_v(0);
    __syncthreads();   // vmcnt(0) drain -> K tile 0 visible

    const int prow = (pair * 32 + lm);  // this lane's q row within block

    for (int t = 0; t < NT_; ++t) {
        const int kb = t * BN_;
        char* kcur = lds_raw + (t & 1) * KB_BYTES;
        // issue DMA for next K tile into the other buffer (drained at B4)
        if (t + 1 < NT_) stage_k(kb + BN_, lds_raw + ((t + 1) & 1) * KB_BYTES);

        // ---- S^T tile (32k x 32q): A = K rows kq*32+lm (swizzled read), B = qf
        f32x16 s;
#pragma unroll
        for (int j = 0; j < 16; ++j) s[j] = 0.0f;
#pragma unroll
        for (int ks = 0; ks < 16; ++ks) {
            const int gsw = (2 * ks + lh) ^ lm;   // 32 lanes -> 32 distinct granules
            f16x8 kf = *(const f16x8*)(kcur + (kq * 32 + lm) * 512 + gsw * 16);
            s = __builtin_amdgcn_mfma_f32_32x32x16_f16(kf, qf[ks], s, 0, 0, 0);
        }

        // ---- partial max over this wave's 32 k (per lane: q = lm) ----
        float pm = s[0];
#pragma unroll
        for (int j = 1; j < 16; ++j) pm = fmaxf(pm, s[j]);
        pm = fmaxf(pm, __shfl_xor(pm, 32, 64));
        if (lh == 0) smax[prow * 4 + kq] = pm;

        // B3: raw barrier, LDS-only drain (K-DMA + V prefetch stay in flight)
        asm volatile("s_waitcnt lgkmcnt(0)" ::: "memory");
        __builtin_amdgcn_s_barrier();
        asm volatile("" ::: "memory");

        const float4 m4 = *(const float4*)&smax[prow * 4];
        const float gm = fmaxf(fmaxf(m4.x, m4.y), fmaxf(m4.z, m4.w));

        // ---- defer-max: only rescale when growth > 8 (uniform across waves)
        float alpha = 1.0f;
        if (__any(gm > mstat + 8.0f)) {
            const float mn = fmaxf(mstat, gm);
            alpha = __expf(mstat - mn);
            mstat = mn;
#pragma unroll
            for (int dt = 0; dt < 2; ++dt)
#pragma unroll
                for (int j = 0; j < 16; ++j) oacc[dt][j] *= alpha;
        }
        const float mloc = mstat;

        // ---- exp (fp16-rounded for num/denom consistency), write P^T tile,
        //      partial sum ----
        float psum = 0.0f;
#pragma unroll
        for (int g = 0; g < 4; ++g) {
            u16x4 pk;
#pragma unroll
            for (int j = 0; j < 4; ++j) {
                const unsigned short hh = f2h(__expf(s[g * 4 + j] - mloc));
                pk[j] = hh;
                psum += h2f(hh);
            }
            *(u16x4*)(pbuf + prow * PSTRIDE + (kq * 32 + 8 * g + 4 * lh) * 2) = pk;
        }
        psum += __shfl_xor(psum, 32, 64);
        if (lh == 0) ssum[prow * 4 + kq] = psum;

        // B4: full barrier (vmcnt drain completes next K tile; P+ssum visible)
        __syncthreads();

        const float4 s4 = *(const float4*)&ssum[prow * 4];
        lstat = lstat * alpha + (s4.x + s4.y) + (s4.z + s4.w);

        // ---- O^T += V^T P^T : A = vf (registers), B = P frags from LDS ----
#pragma unroll
        for (int ks2 = 0; ks2 < 8; ++ks2) {
            f16x8 pf = *(const f16x8*)(pbuf + prow * PSTRIDE + ks2 * 32 + lh * 16);
#pragma unroll
            for (int dt = 0; dt < 2; ++dt)
                oacc[dt] = __builtin_amdgcn_mfma_f32_32x32x16_f16(vf[ks2 * 2 + dt], pf,
                                                                  oacc[dt], 0, 0, 0);
        }

        // prefetch next V tile into the (now-dead) vf registers
        if (t + 1 < NT_) load_v(kb + BN_);
    }

    // ---- finalize: divide by l (per-lane scalar), write out[b][q][d] fp32 ----
    const float linv = 1.0f / lstat;
    float* orow = out + (size_t)(batch * NQ_ + qb + pair * 32 + lm) * 256;
#pragma unroll
    for (int dt = 0; dt < 2; ++dt) {
#pragma unroll
        for (int g = 0; g < 4; ++g) {
            float4 o4;
            o4.x = oacc[dt][4 * g + 0] * linv;
            o4.y = oacc[dt][4 * g + 1] * linv;
            o4.z = oacc[dt][4 * g + 2] * linv;
            o4.w = oacc[dt][4 * g + 3] * linv;
            *(float4*)(orow + kq * 64 + dt * 32 + 8 * g + 4 * lh) = o4;
        }
    }
}

// ---------------------------------------------------------------------------
extern "C" void kernel_launch(void* const* d_in, const int* in_sizes, int n_in,
                              void* d_out, int out_size, void* d_ws, size_t ws_size,
                              hipStream_t stream) {
    const float* q  = (const float*)d_in[0];
    const float* k  = (const float*)d_in[1];
    const float* v  = (const float*)d_in[2];
    const float* Wq = (const float*)d_in[3];
    const float* bq = (const float*)d_in[4];
    const float* Wk = (const float*)d_in[5];
    const float* bk = (const float*)d_in[6];
    const float* Wv = (const float*)d_in[7];
    const float* bv = (const float*)d_in[8];
    float* out = (float*)d_out;

    unsigned short* wt      = (unsigned short*)d_ws;          // 3 * 256*256 fp16
    unsigned short* q_emb   = wt + 3 * 65536;                 // [16384][256]
    unsigned short* k_emb   = q_emb + (size_t)M_ * DH_;       // [16384][256]
    unsigned short* v_emb_t = k_emb + (size_t)M_ * DH_;       // [2][256][8192]

    wt_conv<<<dim3(4, 4, 3), 256, 0, stream>>>(Wq, Wk, Wv, wt);
    proj<<<dim3(256, 3), 256, 0, stream>>>(q, k, v, bq, bk, bv, wt, q_emb, k_emb, v_emb_t);
    flash<<<256, 512, 0, stream>>>(q_emb, k_emb, v_emb_t, out);
}

// Round 2
// 368.736 us; speedup vs baseline: 1.2810x; 1.2810x over previous
//
#include <hip/hip_runtime.h>

// Problem constants
#define B_   2
#define NQ_  8192
#define NK_  8192
#define DIN_ 256
#define DH_  256
#define M_   (B_ * NQ_)   // 16384 flattened rows

typedef _Float16 f16x8 __attribute__((ext_vector_type(8)));
typedef unsigned short u16x8 __attribute__((ext_vector_type(8)));
typedef unsigned short u16x4 __attribute__((ext_vector_type(4)));
typedef unsigned int  u32x4 __attribute__((ext_vector_type(4)));
typedef float f32x16 __attribute__((ext_vector_type(16)));

// fp32 -> fp16 bits (RTNE via hardware cvt)
__device__ __forceinline__ unsigned short f2h(float f) {
    _Float16 h = (_Float16)f;
    return __builtin_bit_cast(unsigned short, h);
}
__device__ __forceinline__ float h2f(unsigned short u) {
    return (float)__builtin_bit_cast(_Float16, u);
}

// LDS-only barrier: drain lgkmcnt (DS ops), NOT vmcnt — in-flight global
// prefetch loads sail across.  The vmem->LDS staging dependency is enforced
// by the hardware register dependency (kpre/vpre regs -> ds_write), for which
// the compiler emits fine-grained vmcnt(N) waits.  sched_barrier(0) pins the
// raw s_barrier against compiler reordering of DS ops (rule m152/#18).
__device__ __forceinline__ void lgkm_barrier() {
    __builtin_amdgcn_sched_barrier(0);
    asm volatile("s_waitcnt lgkmcnt(0)" ::: "memory");
    __builtin_amdgcn_s_barrier();
    __builtin_amdgcn_sched_barrier(0);
}

// ---------------------------------------------------------------------------
// Kernel 1: weight convert + transpose via LDS tile (both sides coalesced).
// wt[mat][n][k] = fp16(W[mat][k][n]).  grid (4,4,3), block 256.
// ---------------------------------------------------------------------------
__global__ void wt_conv(const float* __restrict__ Wq, const float* __restrict__ Wk,
                        const float* __restrict__ Wv, unsigned short* __restrict__ wt) {
    __shared__ float tile[64][65];
    const int mat = blockIdx.z;
    const int k0 = blockIdx.x * 64, n0 = blockIdx.y * 64;
    const float* W = (mat == 0) ? Wq : (mat == 1) ? Wk : Wv;
#pragma unroll
    for (int p = 0; p < 16; ++p) {
        const int idx = p * 256 + threadIdx.x;
        const int r = idx >> 6, c = idx & 63;
        tile[r][c] = W[(k0 + r) * 256 + n0 + c];
    }
    __syncthreads();
#pragma unroll
    for (int p = 0; p < 16; ++p) {
        const int idx = p * 256 + threadIdx.x;
        const int nr = idx >> 6, kc = idx & 63;
        wt[mat * 65536 + (n0 + nr) * 256 + k0 + kc] = f2h(tile[kc][nr]);
    }
}

// ---------------------------------------------------------------------------
// Kernel 2: projections.  X[16384,256] fp32 @ W[256,256] + b -> fp16.
// mat 0 (q), 1 (k): row-major emb[m][n].  mat 2 (v): transposed v_emb_t[b][d][nq].
// ---------------------------------------------------------------------------
__global__ __launch_bounds__(256) void proj(
    const float* __restrict__ xq, const float* __restrict__ xk, const float* __restrict__ xv,
    const float* __restrict__ bq, const float* __restrict__ bk, const float* __restrict__ bv,
    const unsigned short* __restrict__ wt,
    unsigned short* __restrict__ q_emb, unsigned short* __restrict__ k_emb,
    unsigned short* __restrict__ v_emb_t) {
    const int mat = blockIdx.y;
    const float* x    = (mat == 0) ? xq : (mat == 1) ? xk : xv;
    const float* bias = (mat == 0) ? bq : (mat == 1) ? bk : bv;
    const unsigned short* w = wt + mat * 65536;

    const int tid = threadIdx.x;
    const int l = tid & 63, wv = tid >> 6;
    const int pair = wv >> 1, h = wv & 1;
    const int lm = l & 31, lh = l >> 5;
    const int row0 = blockIdx.x * 64;
    const int m = row0 + pair * 32 + lm;

    f32x16 acc[4];
#pragma unroll
    for (int i = 0; i < 4; ++i)
#pragma unroll
        for (int j = 0; j < 16; ++j) acc[i][j] = 0.0f;

#pragma unroll
    for (int ks = 0; ks < 16; ++ks) {
        const float4* ap = (const float4*)(x + (size_t)m * 256 + ks * 16 + lh * 8);
        float4 a0 = ap[0], a1 = ap[1];
        u16x8 au;
        au[0] = f2h(a0.x); au[1] = f2h(a0.y); au[2] = f2h(a0.z); au[3] = f2h(a0.w);
        au[4] = f2h(a1.x); au[5] = f2h(a1.y); au[6] = f2h(a1.z); au[7] = f2h(a1.w);
        f16x8 af = __builtin_bit_cast(f16x8, au);
#pragma unroll
        for (int nt = 0; nt < 4; ++nt) {
            f16x8 bfr = *(const f16x8*)(w + (h * 128 + nt * 32 + lm) * 256 + ks * 16 + lh * 8);
            acc[nt] = __builtin_amdgcn_mfma_f32_32x32x16_f16(af, bfr, acc[nt], 0, 0, 0);
        }
    }

    if (mat < 2) {
        unsigned short* emb = (mat == 0) ? q_emb : k_emb;
#pragma unroll
        for (int nt = 0; nt < 4; ++nt) {
            const int n = h * 128 + nt * 32 + lm;
            const float bsv = bias[n];
#pragma unroll
            for (int r = 0; r < 16; ++r) {
                const int rl = (r & 3) + 8 * (r >> 2) + 4 * lh;
                emb[(size_t)(row0 + pair * 32 + rl) * 256 + n] = f2h(acc[nt][r] + bsv);
            }
        }
    } else {
        const int batch = row0 >> 13;
        const int nqb = (row0 & 8191) + pair * 32;
#pragma unroll
        for (int nt = 0; nt < 4; ++nt) {
            const int n = h * 128 + nt * 32 + lm;   // output feature d
            const float bsv = bias[n];
            unsigned short* dst = v_emb_t + (size_t)batch * DH_ * NQ_ + (size_t)n * NQ_ + nqb;
#pragma unroll
            for (int g = 0; g < 4; ++g) {
                u16x4 pk;
#pragma unroll
                for (int j = 0; j < 4; ++j) pk[j] = f2h(acc[nt][4 * g + j] + bsv);
                *(u16x4*)(dst + 8 * g + 4 * lh) = pk;   // rows nqb+8g+4lh .. +3
            }
        }
    }
}

// ---------------------------------------------------------------------------
// Kernel 3: flash attention, S^T formulation, BN=128, ZERO S duplication.
// grid 256 (= B * NQ/64), block 512 = 8 waves; role (kq = wv>>1, pair = wv&1).
// Each wave owns one distinct 32k x 32q S^T tile (A = K frags from LDS,
// B = Q frags register-resident).  Cross-wave softmax via tiny LDS stats
// ([pair][q][kq] float4).  PV: wave = d-quarter kq x q-tile pair, zero dup.
// Next K/V tile prefetched into registers right after staging barrier.
// v3 change vs the proven 251us version: all 4 in-loop barriers are now
// LDS-only (lgkmcnt drain, raw s_barrier) -> the 16 global prefetch loads
// issued after B2 stay in flight across B3/B4/B1 and have a full iteration
// of latency cover; their completion is enforced only by the register
// dependency at the next iteration's ds_writes (fine-grained vmcnt(N)).
// All cross-wave LDS hazards (kbuf/vbuf/pbuf/smax/ssum) are DS ops ->
// lgkmcnt(0) + barrier is sufficient; audited per-buffer.
// ---------------------------------------------------------------------------
#define BN_ 128
#define KSTRIDE 528    // 128 rows x (512 + 16)   : 33 granules (odd) -> conflict-free b128
#define VSTRIDE 272    // 256 rows x (256 + 16)   : 17 granules
#define PSTRIDE 272    // 64 rows  x (256 + 16)
#define KBYTES  (128 * KSTRIDE)            // 67584
#define VBYTES  (256 * VSTRIDE)            // 69632
#define PBYTES  (64 * PSTRIDE)             // 17408
#define STAT_OFF (KBYTES + VBYTES + PBYTES)        // 154624 (16B aligned)
#define LDS_TOTAL (STAT_OFF + 2048)                // 156672 <= 160 KiB

__global__ __launch_bounds__(512, 2) void flash(
    const unsigned short* __restrict__ q_emb, const unsigned short* __restrict__ k_emb,
    const unsigned short* __restrict__ v_emb_t, float* __restrict__ out) {
    __shared__ __align__(16) char lds_raw[LDS_TOTAL];
    char* kbuf = lds_raw;                       // [128][528]
    char* vbuf = lds_raw + KBYTES;              // [256][272]
    char* pbuf = lds_raw + KBYTES + VBYTES;     // [64][272]
    float* smax = (float*)(lds_raw + STAT_OFF); // [2][32][4]
    float* ssum = smax + 256;                   // [2][32][4]

    const int tid = threadIdx.x;
    const int l = tid & 63, wv = tid >> 6;      // wv 0..7
    const int kq = wv >> 1, pair = wv & 1;      // k-tile / q-tile role
    const int lm = l & 31, lh = l >> 5;

    const int bx = blockIdx.x;
    const int batch = bx >> 7;
    const int qb = (bx & 127) * 64;

    const unsigned short* kg = k_emb + (size_t)batch * NQ_ * 256;
    const unsigned short* vg = v_emb_t + (size_t)batch * DH_ * NQ_;

    // Q fragments register-resident: q row = qb + pair*32 + lm, all 256 dims.
    const int mrow = batch * NQ_ + qb + pair * 32 + lm;
    f16x8 qf[16];
#pragma unroll
    for (int ks = 0; ks < 16; ++ks)
        qf[ks] = *(const f16x8*)(q_emb + (size_t)mrow * 256 + ks * 16 + lh * 8);

    // O^T accumulator: this wave's d-quarter (kq), q cols = pair tile.
    f32x16 oacc[2];
#pragma unroll
    for (int i = 0; i < 2; ++i)
#pragma unroll
        for (int j = 0; j < 16; ++j) oacc[i][j] = 0.0f;

    float mstat = -3.0e38f, lstat = 0.0f;

    // staging indices (512 threads; K 16 rows/pass x8, V 32 rows/pass x8)
    const int sr = tid >> 5, sc = tid & 31;
    const int vr = tid >> 4, vc = tid & 15;

    // prefetch tile 0 into registers
    u32x4 kpre[8], vpre[8];
#pragma unroll
    for (int p = 0; p < 8; ++p)
        kpre[p] = *(const u32x4*)(kg + (size_t)(p * 16 + sr) * 256 + sc * 8);
#pragma unroll
    for (int p = 0; p < 8; ++p)
        vpre[p] = *(const u32x4*)(vg + (size_t)(p * 32 + vr) * NQ_ + vc * 8);

    for (int kb = 0; kb < NK_; kb += BN_) {
        lgkm_barrier();   // B1: prior kbuf/vbuf/pbuf/stat DS reads done
        // ---- write prefetched K tile [128][256] and Vt tile [256][128] ----
        // (hardware vmcnt waits come from the kpre/vpre register dependency)
#pragma unroll
        for (int p = 0; p < 8; ++p)
            *(u32x4*)(kbuf + (p * 16 + sr) * KSTRIDE + sc * 16) = kpre[p];
#pragma unroll
        for (int p = 0; p < 8; ++p)
            *(u32x4*)(vbuf + (p * 32 + vr) * VSTRIDE + vc * 16) = vpre[p];
        lgkm_barrier();   // B2: tiles visible (ds_writes drained by lgkmcnt)

        // ---- issue next-tile global prefetch (overlaps S/softmax/PV; stays
        //      in flight across B3/B4/B1 since those no longer drain vmcnt) ----
        const int nkb = kb + BN_;
        if (nkb < NK_) {
#pragma unroll
            for (int p = 0; p < 8; ++p)
                kpre[p] = *(const u32x4*)(kg + (size_t)(nkb + p * 16 + sr) * 256 + sc * 8);
#pragma unroll
            for (int p = 0; p < 8; ++p)
                vpre[p] = *(const u32x4*)(vg + (size_t)(p * 32 + vr) * NQ_ + nkb + vc * 8);
        }

        // ---- S^T tile (32k x 32q): A = K rows kq*32+lm, B = qf ----
        f32x16 s;
#pragma unroll
        for (int j = 0; j < 16; ++j) s[j] = 0.0f;
#pragma unroll
        for (int ks = 0; ks < 16; ++ks) {
            f16x8 kf = *(const f16x8*)(kbuf + (kq * 32 + lm) * KSTRIDE + ks * 32 + lh * 16);
            s = __builtin_amdgcn_mfma_f32_32x32x16_f16(kf, qf[ks], s, 0, 0, 0);
        }

        // ---- partial max over this wave's 32 k (per lane: q = lm) ----
        float pm = s[0];
#pragma unroll
        for (int j = 1; j < 16; ++j) pm = fmaxf(pm, s[j]);
        pm = fmaxf(pm, __shfl_xor(pm, 32, 64));
        if (lh == 0) smax[(pair * 32 + lm) * 4 + kq] = pm;
        lgkm_barrier();   // B3: all partial maxes visible

        const float4 m4 = *(const float4*)&smax[(pair * 32 + lm) * 4];
        const float gm = fmaxf(fmaxf(m4.x, m4.y), fmaxf(m4.z, m4.w));
        const float mn = fmaxf(mstat, gm);
        const float alpha = __expf(mstat - mn);
        mstat = mn;

        // ---- exp own tile (fp16-rounded for num/denom consistency),
        //      write P^T tile [q=pair*32+lm][k=kq*32 + ...], partial sum ----
        float psum = 0.0f;
#pragma unroll
        for (int g = 0; g < 4; ++g) {
            u16x4 pk;
#pragma unroll
            for (int j = 0; j < 4; ++j) {
                const unsigned short hh = f2h(__expf(s[g * 4 + j] - mn));
                pk[j] = hh;
                psum += h2f(hh);
            }
            *(u16x4*)(pbuf + (pair * 32 + lm) * PSTRIDE + (kq * 32 + 8 * g + 4 * lh) * 2) = pk;
        }
        psum += __shfl_xor(psum, 32, 64);
        if (lh == 0) ssum[(pair * 32 + lm) * 4 + kq] = psum;
        lgkm_barrier();   // B4: P tiles + partial sums visible

        const float4 s4 = *(const float4*)&ssum[(pair * 32 + lm) * 4];
        lstat = lstat * alpha + (s4.x + s4.y) + (s4.z + s4.w);

        // ---- rescale O by alpha (per-lane scalar) ----
#pragma unroll
        for (int dt = 0; dt < 2; ++dt)
#pragma unroll
            for (int j = 0; j < 16; ++j) oacc[dt][j] *= alpha;

        // ---- O^T += V^T P^T over 128 k : A = Vt frags (d rows), B = P frags ----
#pragma unroll
        for (int ks2 = 0; ks2 < 8; ++ks2) {
            f16x8 pf = *(const f16x8*)(pbuf + (pair * 32 + lm) * PSTRIDE + ks2 * 32 + lh * 16);
#pragma unroll
            for (int dt = 0; dt < 2; ++dt) {
                f16x8 vf = *(const f16x8*)(vbuf + (kq * 64 + dt * 32 + lm) * VSTRIDE + ks2 * 32 + lh * 16);
                oacc[dt] = __builtin_amdgcn_mfma_f32_32x32x16_f16(vf, pf, oacc[dt], 0, 0, 0);
            }
        }
    }

    // ---- finalize: divide by l (per-lane scalar), write out[b][q][d] fp32 ----
    const float linv = 1.0f / lstat;
    float* orow = out + (size_t)(batch * NQ_ + qb + pair * 32 + lm) * 256;
#pragma unroll
    for (int dt = 0; dt < 2; ++dt) {
#pragma unroll
        for (int g = 0; g < 4; ++g) {
            float4 o4;
            o4.x = oacc[dt][4 * g + 0] * linv;
            o4.y = oacc[dt][4 * g + 1] * linv;
            o4.z = oacc[dt][4 * g + 2] * linv;
            o4.w = oacc[dt][4 * g + 3] * linv;
            *(float4*)(orow + kq * 64 + dt * 32 + 8 * g + 4 * lh) = o4;
        }
    }
}

// ---------------------------------------------------------------------------
extern "C" void kernel_launch(void* const* d_in, const int* in_sizes, int n_in,
                              void* d_out, int out_size, void* d_ws, size_t ws_size,
                              hipStream_t stream) {
    const float* q  = (const float*)d_in[0];
    const float* k  = (const float*)d_in[1];
    const float* v  = (const float*)d_in[2];
    const float* Wq = (const float*)d_in[3];
    const float* bq = (const float*)d_in[4];
    const float* Wk = (const float*)d_in[5];
    const float* bk = (const float*)d_in[6];
    const float* Wv = (const float*)d_in[7];
    const float* bv = (const float*)d_in[8];
    float* out = (float*)d_out;

    unsigned short* wt      = (unsigned short*)d_ws;          // 3 * 256*256 fp16
    unsigned short* q_emb   = wt + 3 * 65536;                 // [16384][256]
    unsigned short* k_emb   = q_emb + (size_t)M_ * DH_;       // [16384][256]
    unsigned short* v_emb_t = k_emb + (size_t)M_ * DH_;       // [2][256][8192]

    wt_conv<<<dim3(4, 4, 3), 256, 0, stream>>>(Wq, Wk, Wv, wt);
    proj<<<dim3(256, 3), 256, 0, stream>>>(q, k, v, bq, bk, bv, wt, q_emb, k_emb, v_emb_t);
    flash<<<256, 512, 0, stream>>>(q_emb, k_emb, v_emb_t, out);
}

// Round 3
// 328.568 us; speedup vs baseline: 1.4376x; 1.1222x over previous
//
#include <hip/hip_runtime.h>

// Problem constants
#define B_   2
#define NQ_  8192
#define NK_  8192
#define DIN_ 256
#define DH_  256
#define M_   (B_ * NQ_)   // 16384 flattened rows

typedef _Float16 f16x8 __attribute__((ext_vector_type(8)));
typedef unsigned short u16x8 __attribute__((ext_vector_type(8)));
typedef unsigned short u16x4 __attribute__((ext_vector_type(4)));
typedef unsigned int  u32x4 __attribute__((ext_vector_type(4)));
typedef float f32x16 __attribute__((ext_vector_type(16)));

// fp32 -> fp16 bits (RTNE via hardware cvt)
__device__ __forceinline__ unsigned short f2h(float f) {
    _Float16 h = (_Float16)f;
    return __builtin_bit_cast(unsigned short, h);
}
__device__ __forceinline__ float h2f(unsigned short u) {
    return (float)__builtin_bit_cast(_Float16, u);
}

// ---------------------------------------------------------------------------
// Kernel 1: weight convert + transpose via LDS tile (both sides coalesced).
// wt[mat][n][k] = fp16(W[mat][k][n]).  grid (4,4,3), block 256.  (unchanged)
// ---------------------------------------------------------------------------
__global__ void wt_conv(const float* __restrict__ Wq, const float* __restrict__ Wk,
                        const float* __restrict__ Wv, unsigned short* __restrict__ wt) {
    __shared__ float tile[64][65];
    const int mat = blockIdx.z;
    const int k0 = blockIdx.x * 64, n0 = blockIdx.y * 64;
    const float* W = (mat == 0) ? Wq : (mat == 1) ? Wk : Wv;
#pragma unroll
    for (int p = 0; p < 16; ++p) {
        const int idx = p * 256 + threadIdx.x;
        const int r = idx >> 6, c = idx & 63;
        tile[r][c] = W[(k0 + r) * 256 + n0 + c];
    }
    __syncthreads();
#pragma unroll
    for (int p = 0; p < 16; ++p) {
        const int idx = p * 256 + threadIdx.x;
        const int nr = idx >> 6, kc = idx & 63;
        wt[mat * 65536 + (n0 + nr) * 256 + k0 + kc] = f2h(tile[kc][nr]);
    }
}

// ---------------------------------------------------------------------------
// Kernel 2: projections.  X[16384,256] fp32 @ W[256,256] + b -> fp16.
// mat 0 (q), 1 (k): row-major emb[m][n].
// mat 2 (v): fragment-packed vpack[b][kt][dg][lane][j] so flash's PV A-operand
// loads are contiguous 1KB per wave.  Element (lane l, half j) of fragment
// (kt, dg) = V^T[d = dg*32 + (l&31)][k = kt*16 + (l>>5)*8 + j]
//          = v_emb[m = kt*16 + (l>>5)*8 + j][n = dg*32 + (l&31)].
// From the verified C/D layout (m = row0+pair*32+rl, rl=(r&3)+8*(r>>2)+4*lh,
// n = h*128+nt*32+lm) with r = 4g+i:  kt = base_kt + (g>>1),
// frag-lane = (g&1)*32 + lm, frag-half = i + 4*lh  -> u16x4 store, and the
// wave's 64 lanes cover a dense 512B block (fully coalesced; the old layout
// scattered 8B chunks at 16KB stride).
// ---------------------------------------------------------------------------
__global__ __launch_bounds__(256) void proj(
    const float* __restrict__ xq, const float* __restrict__ xk, const float* __restrict__ xv,
    const float* __restrict__ bq, const float* __restrict__ bk, const float* __restrict__ bv,
    const unsigned short* __restrict__ wt,
    unsigned short* __restrict__ q_emb, unsigned short* __restrict__ k_emb,
    unsigned short* __restrict__ vpack) {
    const int mat = blockIdx.y;
    const float* x    = (mat == 0) ? xq : (mat == 1) ? xk : xv;
    const float* bias = (mat == 0) ? bq : (mat == 1) ? bk : bv;
    const unsigned short* w = wt + mat * 65536;

    const int tid = threadIdx.x;
    const int l = tid & 63, wv = tid >> 6;
    const int pair = wv >> 1, h = wv & 1;
    const int lm = l & 31, lh = l >> 5;
    const int row0 = blockIdx.x * 64;
    const int m = row0 + pair * 32 + lm;

    f32x16 acc[4];
#pragma unroll
    for (int i = 0; i < 4; ++i)
#pragma unroll
        for (int j = 0; j < 16; ++j) acc[i][j] = 0.0f;

#pragma unroll
    for (int ks = 0; ks < 16; ++ks) {
        const float4* ap = (const float4*)(x + (size_t)m * 256 + ks * 16 + lh * 8);
        float4 a0 = ap[0], a1 = ap[1];
        u16x8 au;
        au[0] = f2h(a0.x); au[1] = f2h(a0.y); au[2] = f2h(a0.z); au[3] = f2h(a0.w);
        au[4] = f2h(a1.x); au[5] = f2h(a1.y); au[6] = f2h(a1.z); au[7] = f2h(a1.w);
        f16x8 af = __builtin_bit_cast(f16x8, au);
#pragma unroll
        for (int nt = 0; nt < 4; ++nt) {
            f16x8 bfr = *(const f16x8*)(w + (h * 128 + nt * 32 + lm) * 256 + ks * 16 + lh * 8);
            acc[nt] = __builtin_amdgcn_mfma_f32_32x32x16_f16(af, bfr, acc[nt], 0, 0, 0);
        }
    }

    if (mat < 2) {
        unsigned short* emb = (mat == 0) ? q_emb : k_emb;
#pragma unroll
        for (int nt = 0; nt < 4; ++nt) {
            const int n = h * 128 + nt * 32 + lm;
            const float bsv = bias[n];
#pragma unroll
            for (int r = 0; r < 16; ++r) {
                const int rl = (r & 3) + 8 * (r >> 2) + 4 * lh;
                emb[(size_t)(row0 + pair * 32 + rl) * 256 + n] = f2h(acc[nt][r] + bsv);
            }
        }
    } else {
        const int batch = row0 >> 13;
        const int m0 = (row0 & 8191) + pair * 32;   // v-row (k index) base
        unsigned short* vp = vpack + (size_t)batch * (512 * 8 * 64 * 8);
        const int base_kt = m0 >> 4;
#pragma unroll
        for (int nt = 0; nt < 4; ++nt) {
            const int dg = h * 4 + nt;              // d-group = n >> 5
            const int n = h * 128 + nt * 32 + lm;
            const float bsv = bias[n];
#pragma unroll
            for (int g = 0; g < 4; ++g) {
                u16x4 pk;
#pragma unroll
                for (int i = 0; i < 4; ++i) pk[i] = f2h(acc[nt][4 * g + i] + bsv);
                const int kt = base_kt + (g >> 1);
                const int lane = (g & 1) * 32 + lm;
                *(u16x4*)(vp + ((size_t)(kt * 8 + dg) * 64 + lane) * 8 + lh * 4) = pk;
            }
        }
    }
}

// ---------------------------------------------------------------------------
// Kernel 3: flash attention v4.  S^T formulation, BN=128, 8 waves.
//   - K staged via global_load_lds (dwordx4) into a DOUBLE buffer; XOR granule
//     swizzle folded into the *global source* address (LDS dest linear, as the
//     DMA requires); reads apply the same swizzle.  Proven correct in v2 run.
//     No prefetch registers -> nothing for the compiler to sink.
//   - V fragments direct from global (L2-resident) in the fragment-packed
//     vpack layout -> 16 fully-coalesced 1KB wave-loads per iter.  No V LDS.
//   - LDS traffic/iter: 464KB -> ~272KB (K dma-write 64K + K read 128K +
//     P 16K+64K + stats).  2 __syncthreads per iter (hazards audited:
//     smax WAR fenced by B4(t-1), ssum/pbuf WAR by B3(t), kbuf WAR by B4).
// ---------------------------------------------------------------------------
#define BN_ 128
#define NT_ (NK_ / BN_)                    // 64 iterations
#define KB_BYTES 65536                     // 128 rows x 512B (swizzled granules)
#define PSTRIDE 272                        // 64 rows x (256 + 16) : proven pad
#define PBYTES  (64 * PSTRIDE)             // 17408
#define STAT_OFF (2 * KB_BYTES + PBYTES)   // 148480
#define LDS_TOTAL (STAT_OFF + 2048)        // 150528 <= 160 KiB

__global__ __launch_bounds__(512, 2) void flash(
    const unsigned short* __restrict__ q_emb, const unsigned short* __restrict__ k_emb,
    const unsigned short* __restrict__ vpack, float* __restrict__ out) {
    __shared__ __align__(16) char lds_raw[LDS_TOTAL];
    char* pbuf = lds_raw + 2 * KB_BYTES;        // [64][272]
    float* smax = (float*)(lds_raw + STAT_OFF); // [2][32][4]
    float* ssum = smax + 256;                   // [2][32][4]

    const int tid = threadIdx.x;
    const int l = tid & 63, wv = tid >> 6;      // wv 0..7
    const int kq = wv >> 1, pair = wv & 1;      // k-tile / q-tile role
    const int lm = l & 31, lh = l >> 5;

    const int bx = blockIdx.x;
    const int batch = bx >> 7;
    const int qb = (bx & 127) * 64;

    const unsigned short* kg = k_emb + (size_t)batch * NK_ * 256;
    const unsigned short* vp = vpack + (size_t)batch * (512 * 8 * 64 * 8);

    // Q fragments register-resident: q row = qb + pair*32 + lm, all 256 dims.
    const int mrow = batch * NQ_ + qb + pair * 32 + lm;
    f16x8 qf[16];
#pragma unroll
    for (int ks = 0; ks < 16; ++ks)
        qf[ks] = *(const f16x8*)(q_emb + (size_t)mrow * 256 + ks * 16 + lh * 8);

    // O^T accumulator: this wave's d-quarter (kq), q cols = pair tile.
    f32x16 oacc[2];
#pragma unroll
    for (int i = 0; i < 2; ++i)
#pragma unroll
        for (int j = 0; j < 16; ++j) oacc[i][j] = 0.0f;

    float mstat = -3.0e38f, lstat = 0.0f;

    // ---- K staging via global_load_lds: wave wv owns rows wv*16..wv*16+15.
    // LDS[r][g] = global[r][g ^ (r&31)] (granule = 16B); dest linear per DMA
    // rules, swizzle on the per-lane SOURCE address.
    const int rlane = l >> 5;                  // +0/+1 row within 1KB chunk
    const int gl = l & 31;                     // linear granule this lane fills
    auto stage_k = [&](int kb, char* kdst) {
#pragma unroll
        for (int p = 0; p < 8; ++p) {
            const int r0 = wv * 16 + 2 * p;            // wave-uniform base row
            const int r = r0 + rlane;
            const int gsw = gl ^ (r & 31);             // source granule
            const unsigned short* src = kg + (size_t)(kb + r) * 256 + gsw * 8;
            __builtin_amdgcn_global_load_lds(
                (const __attribute__((address_space(1))) void*)src,
                (__attribute__((address_space(3))) void*)(kdst + r0 * 512),
                16, 0, 0);
        }
    };

    // ---- V fragments direct-from-global (fragment-packed, coalesced 1KB/instr)
    // vf[ks2*2+dt] = fragment (kt = kb/16 + ks2, dg = kq*2 + dt), lane l.
    f16x8 vf[16];
    auto load_v = [&](int kb) {
        const size_t kt0 = (size_t)(kb >> 4);
#pragma unroll
        for (int ks2 = 0; ks2 < 8; ++ks2)
#pragma unroll
            for (int dt = 0; dt < 2; ++dt)
                vf[ks2 * 2 + dt] = *(const f16x8*)(
                    vp + (((kt0 + ks2) * 8 + kq * 2 + dt) * 64 + l) * 8);
    };

    // prologue: K tile 0
    stage_k(0, lds_raw);
    __syncthreads();   // vmcnt(0) drain -> K tile 0 visible

    const int prow = pair * 32 + lm;  // this lane's q row within block

    for (int t = 0; t < NT_; ++t) {
        const int kb = t * BN_;
        char* kcur = lds_raw + (t & 1) * KB_BYTES;
        // issue DMA for next K tile into the other buffer (covered by S-phase)
        if (t + 1 < NT_) stage_k(kb + BN_, lds_raw + ((t + 1) & 1) * KB_BYTES);
        // issue this tile's V fragment loads (covered by S + softmax phases)
        load_v(kb);

        // ---- S^T tile (32k x 32q): A = K rows kq*32+lm (swizzled), B = qf ----
        f32x16 s;
#pragma unroll
        for (int j = 0; j < 16; ++j) s[j] = 0.0f;
#pragma unroll
        for (int ks = 0; ks < 16; ++ks) {
            const int gsw = (2 * ks + lh) ^ lm;   // 32 lanes -> 32 distinct granules
            f16x8 kf = *(const f16x8*)(kcur + (kq * 32 + lm) * 512 + gsw * 16);
            s = __builtin_amdgcn_mfma_f32_32x32x16_f16(kf, qf[ks], s, 0, 0, 0);
        }

        // ---- partial max over this wave's 32 k (per lane: q = lm) ----
        float pm = s[0];
#pragma unroll
        for (int j = 1; j < 16; ++j) pm = fmaxf(pm, s[j]);
        pm = fmaxf(pm, __shfl_xor(pm, 32, 64));
        if (lh == 0) smax[prow * 4 + kq] = pm;
        __syncthreads();   // B3: partial maxes visible (also drains K-DMA, vf)

        const float4 m4 = *(const float4*)&smax[prow * 4];
        const float gm = fmaxf(fmaxf(m4.x, m4.y), fmaxf(m4.z, m4.w));
        const float mn = fmaxf(mstat, gm);
        const float alpha = __expf(mstat - mn);
        mstat = mn;

        // ---- exp (fp16-rounded for num/denom consistency), write P^T tile,
        //      partial sum ----
        float psum = 0.0f;
#pragma unroll
        for (int g = 0; g < 4; ++g) {
            u16x4 pk;
#pragma unroll
            for (int j = 0; j < 4; ++j) {
                const unsigned short hh = f2h(__expf(s[g * 4 + j] - mn));
                pk[j] = hh;
                psum += h2f(hh);
            }
            *(u16x4*)(pbuf + prow * PSTRIDE + (kq * 32 + 8 * g + 4 * lh) * 2) = pk;
        }
        psum += __shfl_xor(psum, 32, 64);
        if (lh == 0) ssum[prow * 4 + kq] = psum;
        __syncthreads();   // B4: P tiles + partial sums visible

        const float4 s4 = *(const float4*)&ssum[prow * 4];
        lstat = lstat * alpha + (s4.x + s4.y) + (s4.z + s4.w);

        // ---- rescale O by alpha (per-lane scalar) ----
#pragma unroll
        for (int dt = 0; dt < 2; ++dt)
#pragma unroll
            for (int j = 0; j < 16; ++j) oacc[dt][j] *= alpha;

        // ---- O^T += V^T P^T : A = vf (registers), B = P frags from LDS ----
#pragma unroll
        for (int ks2 = 0; ks2 < 8; ++ks2) {
            f16x8 pf = *(const f16x8*)(pbuf + prow * PSTRIDE + ks2 * 32 + lh * 16);
#pragma unroll
            for (int dt = 0; dt < 2; ++dt)
                oacc[dt] = __builtin_amdgcn_mfma_f32_32x32x16_f16(vf[ks2 * 2 + dt], pf,
                                                                  oacc[dt], 0, 0, 0);
        }
    }

    // ---- finalize: divide by l (per-lane scalar), write out[b][q][d] fp32 ----
    const float linv = 1.0f / lstat;
    float* orow = out + (size_t)(batch * NQ_ + qb + pair * 32 + lm) * 256;
#pragma unroll
    for (int dt = 0; dt < 2; ++dt) {
#pragma unroll
        for (int g = 0; g < 4; ++g) {
            float4 o4;
            o4.x = oacc[dt][4 * g + 0] * linv;
            o4.y = oacc[dt][4 * g + 1] * linv;
            o4.z = oacc[dt][4 * g + 2] * linv;
            o4.w = oacc[dt][4 * g + 3] * linv;
            *(float4*)(orow + kq * 64 + dt * 32 + 8 * g + 4 * lh) = o4;
        }
    }
}

// ---------------------------------------------------------------------------
extern "C" void kernel_launch(void* const* d_in, const int* in_sizes, int n_in,
                              void* d_out, int out_size, void* d_ws, size_t ws_size,
                              hipStream_t stream) {
    const float* q  = (const float*)d_in[0];
    const float* k  = (const float*)d_in[1];
    const float* v  = (const float*)d_in[2];
    const float* Wq = (const float*)d_in[3];
    const float* bq = (const float*)d_in[4];
    const float* Wk = (const float*)d_in[5];
    const float* bk = (const float*)d_in[6];
    const float* Wv = (const float*)d_in[7];
    const float* bv = (const float*)d_in[8];
    float* out = (float*)d_out;

    unsigned short* wt      = (unsigned short*)d_ws;          // 3 * 256*256 fp16
    unsigned short* q_emb   = wt + 3 * 65536;                 // [16384][256]
    unsigned short* k_emb   = q_emb + (size_t)M_ * DH_;       // [16384][256]
    unsigned short* vpack   = k_emb + (size_t)M_ * DH_;       // [2][512][8][64][8]

    wt_conv<<<dim3(4, 4, 3), 256, 0, stream>>>(Wq, Wk, Wv, wt);
    proj<<<dim3(256, 3), 256, 0, stream>>>(q, k, v, bq, bk, bv, wt, q_emb, k_emb, vpack);
    flash<<<256, 512, 0, stream>>>(q_emb, k_emb, vpack, out);
}